// Round 13
// baseline (20.920 us; speedup 1.0000x reference)
//
#include <hip/hip_runtime.h>

// Dihedral2Coord — R11's 2×W32-segment packed scan + 2-deep molecule pipeline
// per segment. Per block (128 thr = 2 waves): 2 waves × 2 segments × 2
// pipelined molecules = 8 molecules; grid 512 -> 2 blocks/CU.
// Phase overlap: at t0 issue mol-A head+tails+theta and mol-B head+theta;
// scan/emit/store A; issue B tails; scan/emit/store B. Store-A drains under
// scan-B; B cold reads stream under scan-A.
//
// final[m] = P_{m-3}(pos0[m]); P_k = B_0∘...∘B_k (LOCAL-frame step rotations;
// dihedrals are rigid-invariant so phi_k comes from pos0 alone).

#define NK 128
#define NM 512
#define NMOL 4096
#define TPB 128

struct Aff { float qw, qx, qy, qz, tx, ty, tz; };

__device__ __forceinline__ void qrot(float qw, float qx, float qy, float qz,
                                     float vx, float vy, float vz,
                                     float& ox, float& oy, float& oz) {
    const float ux = qy*vz - qz*vy + qw*vx;
    const float uy = qz*vx - qx*vz + qw*vy;
    const float uz = qx*vy - qy*vx + qw*vz;
    ox = vx + 2.f*(qy*uz - qz*uy);
    oy = vy + 2.f*(qz*ux - qx*uz);
    oz = vz + 2.f*(qx*uy - qy*ux);
}

// (Q∘P)(x) = Q(P(x))
__device__ __forceinline__ Aff aff_compose(const Aff& Q, const Aff& P) {
    Aff r;
    r.qw = Q.qw*P.qw - Q.qx*P.qx - Q.qy*P.qy - Q.qz*P.qz;
    r.qx = Q.qw*P.qx + Q.qx*P.qw + Q.qy*P.qz - Q.qz*P.qy;
    r.qy = Q.qw*P.qy - Q.qx*P.qz + Q.qy*P.qw + Q.qz*P.qx;
    r.qz = Q.qw*P.qz + Q.qx*P.qy - Q.qy*P.qx + Q.qz*P.qw;
    float rx, ry, rz;
    qrot(Q.qw, Q.qx, Q.qy, Q.qz, P.tx, P.ty, P.tz, rx, ry, rz);
    r.tx = rx + Q.tx; r.ty = ry + Q.ty; r.tz = rz + Q.tz;
    return r;
}

#define SHFL_AFF_UP32(D, S, off)                                         \
    D.qw = __shfl_up(S.qw, off, 32); D.qx = __shfl_up(S.qx, off, 32);    \
    D.qy = __shfl_up(S.qy, off, 32); D.qz = __shfl_up(S.qz, off, 32);    \
    D.tx = __shfl_up(S.tx, off, 32); D.ty = __shfl_up(S.ty, off, 32);    \
    D.tz = __shfl_up(S.tz, off, 32);

// Build B_{4sl+j} from shared bonds/normals (j literal after unroll).
// Validated formula (R10/R11, absmax 0.125).
#define BUILD_STEP(j, OUT) do {                                               \
    const float cxx = ny[(j)+1]*nz[(j)] - nz[(j)+1]*ny[(j)];                  \
    const float cxy = nz[(j)+1]*nx[(j)] - nx[(j)+1]*nz[(j)];                  \
    const float cxz = nx[(j)+1]*ny[(j)] - ny[(j)+1]*nx[(j)];                  \
    const float g   = cxx*vx[(j)+1] + cxy*vy[(j)+1] + cxz*vz[(j)+1];          \
    const float dnn = nx[(j)]*nx[(j)+1] + ny[(j)]*ny[(j)+1] + nz[(j)]*nz[(j)+1]; \
    const float r12 = rsqrtf(fmaxf(Ln[(j)]*Ln[(j)+1], 1e-30f));               \
    const float ira = rsqrtf(fmaxf(Lv[(j)+1], 1e-24f));                       \
    const float cphi = dnn*r12, sphi = g*r12*ira;                             \
    const float sth = __sinf(th[(j)]), cth = __cosf(th[(j)]);                 \
    const float c = cth*cphi - sth*sphi, s = sth*cphi + cth*sphi;             \
    const float hc = sqrtf(fmaxf(0.f, 0.5f*(1.f + c)));                       \
    const float hs = copysignf(sqrtf(fmaxf(0.f, 0.5f*(1.f - c))), s);         \
    const float hsa = hs*ira;                                                 \
    OUT.qw = hc; OUT.qx = vx[(j)+1]*hsa; OUT.qy = vy[(j)+1]*hsa; OUT.qz = vz[(j)+1]*hsa; \
    float rx, ry, rz;                                                         \
    qrot(OUT.qw, OUT.qx, OUT.qy, OUT.qz, A[3*(j)+3], A[3*(j)+4], A[3*(j)+5], rx, ry, rz); \
    OUT.tx = A[3*(j)+3]-rx; OUT.ty = A[3*(j)+4]-ry; OUT.tz = A[3*(j)+5]-rz;   \
} while (0)

__global__ __launch_bounds__(TPB, 1) void dihedral_pipe_seg_kernel(
    const float* __restrict__ theta,  // (NMOL, NK)
    const float* __restrict__ pos0,   // (NMOL, NM, 3)
    float* __restrict__ out)          // (NMOL, NM, 3)
{
    const int tid  = threadIdx.x;
    const int lane = tid & 63;
    const int wid  = tid >> 6;       // 0..1
    const int seg  = lane >> 5;      // 0..1
    const int sl   = lane & 31;
    const int base = (blockIdx.x * 2 + wid) * 4 + seg * 2;
    const int molA = base, molB = base + 1;

    const float4* __restrict__ pbA = (const float4*)(pos0 + (size_t)molA * (NM*3));
    float4*       __restrict__ obA = (float4*)(out  + (size_t)molA * (NM*3));
    const float4* __restrict__ pbB = (const float4*)(pos0 + (size_t)molB * (NM*3));
    float4*       __restrict__ obB = (float4*)(out  + (size_t)molB * (NM*3));

    __shared__ float sAm[2][2][400];   // [wid][seg]: pos0 atoms 0..131 (reused A->B)
    __shared__ float sOm[2][2][400];   // final atoms 0..131
    float* __restrict__ sa = sAm[wid][seg];
    float* __restrict__ so = sOm[wid][seg];

    const bool ex   = (sl < 3);
    const bool has3 = (sl < 31);

    // ---- per-molecule phase: stage head, dual-seg W32 scan, emit, store ----
    auto PHASE = [&](float4 h0, float4 h1, float4 h2, float4 h3,
                     const float4 th4, const float4* T, float4* __restrict__ ob4) {
        float4* sa4 = (float4*)sa;
        sa4[sl] = h0; sa4[sl + 32] = h1; sa4[sl + 64] = h2;
        if (ex) sa4[96 + sl] = h3;
        // same-wave DS ordering: no barrier

        float A[21];
        {
            const float2* ap2 = (const float2*)&sa[sl * 12];
            #pragma unroll
            for (int i = 0; i < 10; ++i) { const float2 v = ap2[i]; A[2*i] = v.x; A[2*i+1] = v.y; }
            A[20] = sa[sl * 12 + 20];
        }
        float vx[6], vy[6], vz[6];
        #pragma unroll
        for (int i = 0; i < 6; ++i) {
            vx[i] = A[3*i+3] - A[3*i];
            vy[i] = A[3*i+4] - A[3*i+1];
            vz[i] = A[3*i+5] - A[3*i+2];
        }
        float nx[5], ny[5], nz[5], Ln[5];
        #pragma unroll
        for (int i = 0; i < 5; ++i) {
            nx[i] = vy[i]*vz[i+1] - vz[i]*vy[i+1];
            ny[i] = vz[i]*vx[i+1] - vx[i]*vz[i+1];
            nz[i] = vx[i]*vy[i+1] - vy[i]*vx[i+1];
            Ln[i] = nx[i]*nx[i] + ny[i]*ny[i] + nz[i]*nz[i];
        }
        float Lv[5];
        #pragma unroll
        for (int i = 1; i < 5; ++i) Lv[i] = vx[i]*vx[i] + vy[i]*vy[i] + vz[i]*vz[i];
        const float th[4] = {th4.x, th4.y, th4.z, th4.w};

        Aff B0;   BUILD_STEP(0, B0);
        Aff Bt;   BUILD_STEP(1, Bt);
        Aff C01  = aff_compose(B0, Bt);
        BUILD_STEP(2, Bt);
        Aff C012 = aff_compose(C01, Bt);
        BUILD_STEP(3, Bt);
        Aff S    = aff_compose(C012, Bt);

        #pragma unroll
        for (int off = 1; off < 32; off <<= 1) {
            Aff Q; SHFL_AFF_UP32(Q, S, off);
            if (sl >= off) S = aff_compose(Q, S);
        }
        Aff E; SHFL_AFF_UP32(E, S, 1);
        if (sl == 0) { E.qw = 1.f; E.qx = E.qy = E.qz = 0.f; E.tx = E.ty = E.tz = 0.f; }
        const Aff P0 = aff_compose(E, B0);
        const Aff P1 = aff_compose(E, C01);
        const Aff P2 = aff_compose(E, C012);

        {
            float ox, oy, oz;
            float* op = &so[12*sl + 9];
            qrot(P0.qw, P0.qx, P0.qy, P0.qz, A[9],  A[10], A[11], ox, oy, oz);
            op[0] = ox + P0.tx; op[1] = oy + P0.ty; op[2] = oz + P0.tz;
            qrot(P1.qw, P1.qx, P1.qy, P1.qz, A[12], A[13], A[14], ox, oy, oz);
            op[3] = ox + P1.tx; op[4] = oy + P1.ty; op[5] = oz + P1.tz;
            qrot(P2.qw, P2.qx, P2.qy, P2.qz, A[15], A[16], A[17], ox, oy, oz);
            op[6] = ox + P2.tx; op[7] = oy + P2.ty; op[8] = oz + P2.tz;
            qrot(S.qw, S.qx, S.qy, S.qz, A[18], A[19], A[20], ox, oy, oz);
            op[9] = ox + S.tx;  op[10] = oy + S.ty; op[11] = oz + S.tz;
        }
        if (sl < 9) so[sl] = sa[sl];               // atoms 0..2 never move
        if (sl == 31) {                            // atom 131 = P_127(pos0[131])
            float ox, oy, oz;
            qrot(S.qw, S.qx, S.qy, S.qz, sa[393], sa[394], sa[395], ox, oy, oz);
            so[393] = ox + S.tx; so[394] = oy + S.ty; so[395] = oz + S.tz;
        }

        // F = P_127 broadcast within segment
        Aff F;
        F.qw = __shfl(S.qw, 31, 32); F.qx = __shfl(S.qx, 31, 32);
        F.qy = __shfl(S.qy, 31, 32); F.qz = __shfl(S.qz, 31, 32);
        F.tx = __shfl(S.tx, 31, 32); F.ty = __shfl(S.ty, 31, 32);
        F.tz = __shfl(S.tz, 31, 32);
        const float f00 = 1.f - 2.f*(F.qy*F.qy + F.qz*F.qz);
        const float f01 = 2.f*(F.qx*F.qy - F.qw*F.qz);
        const float f02 = 2.f*(F.qx*F.qz + F.qw*F.qy);
        const float f10 = 2.f*(F.qx*F.qy + F.qw*F.qz);
        const float f11 = 1.f - 2.f*(F.qx*F.qx + F.qz*F.qz);
        const float f12 = 2.f*(F.qy*F.qz - F.qw*F.qx);
        const float f20 = 2.f*(F.qx*F.qz - F.qw*F.qy);
        const float f21 = 2.f*(F.qy*F.qz + F.qw*F.qx);
        const float f22 = 1.f - 2.f*(F.qx*F.qx + F.qy*F.qy);

        // store head (99 f4)
        const float4* so4 = (const float4*)so;
        ob4[sl] = so4[sl]; ob4[sl + 32] = so4[sl + 32]; ob4[sl + 64] = so4[sl + 64];
        if (ex) ob4[96 + sl] = so4[96 + sl];

        // tails: 3 f4-triples per lane (tasks sl, sl+32, sl+64<95)
        #define TAIL_EMIT(b, va, vb, vc)                                      \
        do {                                                                  \
            const float x0=va.x, y0=va.y, z0=va.z;                            \
            const float x1=va.w, y1=vb.x, z1=vb.y;                            \
            const float x2=vb.z, y2=vb.w, z2=vc.x;                            \
            const float x3=vc.y, y3=vc.z, z3=vc.w;                            \
            float4 o0, o1, o2;                                                \
            o0.x = f00*x0+f01*y0+f02*z0+F.tx; o0.y = f10*x0+f11*y0+f12*z0+F.ty; \
            o0.z = f20*x0+f21*y0+f22*z0+F.tz; o0.w = f00*x1+f01*y1+f02*z1+F.tx; \
            o1.x = f10*x1+f11*y1+f12*z1+F.ty; o1.y = f20*x1+f21*y1+f22*z1+F.tz; \
            o1.z = f00*x2+f01*y2+f02*z2+F.tx; o1.w = f10*x2+f11*y2+f12*z2+F.ty; \
            o2.x = f20*x2+f21*y2+f22*z2+F.tz; o2.y = f00*x3+f01*y3+f02*z3+F.tx; \
            o2.z = f10*x3+f11*y3+f12*z3+F.ty; o2.w = f20*x3+f21*y3+f22*z3+F.tz; \
            ob4[(b)] = o0; ob4[(b)+1] = o1; ob4[(b)+2] = o2;                  \
        } while (0)
        TAIL_EMIT(99 + 3*sl,        T[0], T[1], T[2]);
        TAIL_EMIT(99 + 3*(sl + 32), T[3], T[4], T[5]);
        if (has3) TAIL_EMIT(99 + 3*(sl + 64), T[6], T[7], T[8]);
        #undef TAIL_EMIT
    };

    // ---- t0: mol A full load set + mol B head/theta ----
    float4 hA0 = pbA[sl], hA1 = pbA[sl + 32], hA2 = pbA[sl + 64];
    float4 hA3; if (ex) hA3 = pbA[96 + sl];
    const float4 thA4 = ((const float4*)(theta + (size_t)molA * NK))[sl];
    float4 TA[9];
    { const int b = 99 + 3*sl;        TA[0] = pbA[b]; TA[1] = pbA[b+1]; TA[2] = pbA[b+2]; }
    { const int b = 99 + 3*(sl + 32); TA[3] = pbA[b]; TA[4] = pbA[b+1]; TA[5] = pbA[b+2]; }
    if (has3) { const int b = 99 + 3*(sl + 64); TA[6] = pbA[b]; TA[7] = pbA[b+1]; TA[8] = pbA[b+2]; }
    float4 hB0 = pbB[sl], hB1 = pbB[sl + 32], hB2 = pbB[sl + 64];
    float4 hB3; if (ex) hB3 = pbB[96 + sl];
    const float4 thB4 = ((const float4*)(theta + (size_t)molB * NK))[sl];

    // ---- phase A (B head loads in flight) ----
    PHASE(hA0, hA1, hA2, hA3, thA4, TA, obA);

    // ---- issue B tails; their latency hides under phase-B's scan ----
    float4 TB[9];
    { const int b = 99 + 3*sl;        TB[0] = pbB[b]; TB[1] = pbB[b+1]; TB[2] = pbB[b+2]; }
    { const int b = 99 + 3*(sl + 32); TB[3] = pbB[b]; TB[4] = pbB[b+1]; TB[5] = pbB[b+2]; }
    if (has3) { const int b = 99 + 3*(sl + 64); TB[6] = pbB[b]; TB[7] = pbB[b+1]; TB[8] = pbB[b+2]; }

    // ---- phase B (store-A drains underneath) ----
    PHASE(hB0, hB1, hB2, hB3, thB4, TB, obB);
}

extern "C" void kernel_launch(void* const* d_in, const int* in_sizes, int n_in,
                              void* d_out, int out_size, void* d_ws, size_t ws_size,
                              hipStream_t stream) {
    const float* theta = (const float*)d_in[0];  // input (N,K) fp32
    const float* pos0  = (const float*)d_in[1];  // pos0 (N,M,3) fp32
    float* out = (float*)d_out;                  // (N,M,3) fp32
    dihedral_pipe_seg_kernel<<<NMOL / 8, TPB, 0, stream>>>(theta, pos0, out);
}

// Round 14
// 17.201 us; speedup vs baseline: 1.2162x; 1.2162x over previous
//
#include <hip/hip_runtime.h>

// Dihedral2Coord — quat-only scan + parallel translation recurrence.
// Key identity: B_{k-1},B_k both fix pos0[k+1] => P_k(pos0[k+1]) = final[k+1],
// so final[k+3] = R(P_k)·(pos0[k+3]-pos0[k+1]) + final[k+1]. The affine scan
// (7 shfl + 49 ops/round) becomes: quat scan (4 shfl + 28 ops) + per-lane
// d_k = R(P_k)·chord_k + two float3 prefix-sums (6 shfl + 6 adds).
// Packing: R11's best structure — 2 molecules/wave as W32 segments, lane sl
// owns steps 4sl..4sl+3; 8 waves/CU; all global loads issued up front.

#define NK 128
#define NM 512
#define NMOL 4096
#define TPB 256
#define WPB 4        // waves per block
#define MPW 2        // molecules per wave (two 32-lane segments)
// grid = NMOL/(WPB*MPW) = 512

struct Q4 { float w, x, y, z; };

// R(a⊗b) = R(a)R(b)  (b applied first) — matches prefix order P = earlier⊗later
__device__ __forceinline__ Q4 qmul(const Q4& a, const Q4& b) {
    Q4 r;
    r.w = a.w*b.w - a.x*b.x - a.y*b.y - a.z*b.z;
    r.x = a.w*b.x + a.x*b.w + a.y*b.z - a.z*b.y;
    r.y = a.w*b.y - a.x*b.z + a.y*b.w + a.z*b.x;
    r.z = a.w*b.z + a.x*b.y - a.y*b.x + a.z*b.w;
    return r;
}

__device__ __forceinline__ void qrotv(const Q4& q, float vx, float vy, float vz,
                                      float& ox, float& oy, float& oz) {
    const float ux = q.y*vz - q.z*vy + q.w*vx;
    const float uy = q.z*vx - q.x*vz + q.w*vy;
    const float uz = q.x*vy - q.y*vx + q.w*vz;
    ox = vx + 2.f*(q.y*uz - q.z*uy);
    oy = vy + 2.f*(q.z*ux - q.x*uz);
    oz = vz + 2.f*(q.x*uy - q.y*ux);
}

#define SHFL_Q_UP32(D, S, off)                                           \
    D.w = __shfl_up(S.w, off, 32); D.x = __shfl_up(S.x, off, 32);        \
    D.y = __shfl_up(S.y, off, 32); D.z = __shfl_up(S.z, off, 32);

// Step-quat for step 4sl+j (validated sphi/cphi formula, R10-R13; quat only)
#define BUILD_Q(j, OUT) do {                                                  \
    const float cxx = ny[(j)+1]*nz[(j)] - nz[(j)+1]*ny[(j)];                  \
    const float cxy = nz[(j)+1]*nx[(j)] - nx[(j)+1]*nz[(j)];                  \
    const float cxz = nx[(j)+1]*ny[(j)] - ny[(j)+1]*nx[(j)];                  \
    const float g   = cxx*vx[(j)+1] + cxy*vy[(j)+1] + cxz*vz[(j)+1];          \
    const float dnn = nx[(j)]*nx[(j)+1] + ny[(j)]*ny[(j)+1] + nz[(j)]*nz[(j)+1]; \
    const float r12 = rsqrtf(fmaxf(Ln[(j)]*Ln[(j)+1], 1e-30f));               \
    const float ira = rsqrtf(fmaxf(Lv[(j)+1], 1e-24f));                       \
    const float cphi = dnn*r12, sphi = g*r12*ira;                             \
    const float sth = __sinf(th[(j)]), cth = __cosf(th[(j)]);                 \
    const float c = cth*cphi - sth*sphi, s = sth*cphi + cth*sphi;             \
    const float hc = sqrtf(fmaxf(0.f, 0.5f*(1.f + c)));                       \
    const float hs = copysignf(sqrtf(fmaxf(0.f, 0.5f*(1.f - c))), s);         \
    const float hsa = hs*ira;                                                 \
    OUT.w = hc; OUT.x = vx[(j)+1]*hsa; OUT.y = vy[(j)+1]*hsa; OUT.z = vz[(j)+1]*hsa; \
} while (0)

__global__ __launch_bounds__(TPB, 2) void dihedral_qscan_kernel(
    const float* __restrict__ theta,  // (NMOL, NK)
    const float* __restrict__ pos0,   // (NMOL, NM, 3)
    float* __restrict__ out)          // (NMOL, NM, 3)
{
    const int tid  = threadIdx.x;
    const int lane = tid & 63;
    const int wid  = tid >> 6;
    const int seg  = lane >> 5;      // which molecule of this wave
    const int sl   = lane & 31;      // segment lane
    const int mol  = blockIdx.x * (WPB * MPW) + wid * MPW + seg;

    const float4* __restrict__ pb4 = (const float4*)(pos0 + (size_t)mol * (NM*3));
    float4*       __restrict__ ob4 = (float4*)(out  + (size_t)mol * (NM*3));

    __shared__ float sAm[WPB][MPW][400];   // pos0 atoms 0..131
    __shared__ float sOm[WPB][MPW][400];   // final atoms 0..131
    float* __restrict__ sa   = sAm[wid][seg];
    float* __restrict__ sout = sOm[wid][seg];

    // ---- issue ALL global loads up front ----
    const bool ex = (sl < 3);
    float4 h0 = pb4[sl], h1 = pb4[sl + 32], h2 = pb4[sl + 64];
    float4 h3; if (ex) h3 = pb4[96 + sl];
    const float4 th4 = ((const float4*)(theta + (size_t)mol * NK))[sl];
    float4 T0a, T0b, T0c, T1a, T1b, T1c, T2a, T2b, T2c;
    { const int b = 99 + 3*sl;        T0a = pb4[b]; T0b = pb4[b+1]; T0c = pb4[b+2]; }
    { const int b = 99 + 3*(sl + 32); T1a = pb4[b]; T1b = pb4[b+1]; T1c = pb4[b+2]; }
    const bool has3 = (sl < 31);
    if (has3) { const int b = 99 + 3*(sl + 64); T2a = pb4[b]; T2b = pb4[b+1]; T2c = pb4[b+2]; }

    // stage head (same-wave DS ordering, no barrier)
    float4* sa4 = (float4*)sa;
    sa4[sl] = h0; sa4[sl + 32] = h1; sa4[sl + 64] = h2;
    if (ex) sa4[96 + sl] = h3;

    // lane: atoms 4sl..4sl+6 (21 floats)
    float A[21];
    {
        const float2* ap2 = (const float2*)&sa[sl * 12];
        #pragma unroll
        for (int i = 0; i < 10; ++i) { const float2 v = ap2[i]; A[2*i] = v.x; A[2*i+1] = v.y; }
        A[20] = sa[sl * 12 + 20];
    }

    // shared bonds / normals for the 4 steps
    float vx[6], vy[6], vz[6];
    #pragma unroll
    for (int i = 0; i < 6; ++i) {
        vx[i] = A[3*i+3] - A[3*i];
        vy[i] = A[3*i+4] - A[3*i+1];
        vz[i] = A[3*i+5] - A[3*i+2];
    }
    float nx[5], ny[5], nz[5], Ln[5];
    #pragma unroll
    for (int i = 0; i < 5; ++i) {
        nx[i] = vy[i]*vz[i+1] - vz[i]*vy[i+1];
        ny[i] = vz[i]*vx[i+1] - vx[i]*vz[i+1];
        nz[i] = vx[i]*vy[i+1] - vy[i]*vx[i+1];
        Ln[i] = nx[i]*nx[i] + ny[i]*ny[i] + nz[i]*nz[i];
    }
    float Lv[5];
    #pragma unroll
    for (int i = 1; i < 5; ++i) Lv[i] = vx[i]*vx[i] + vy[i]*vy[i] + vz[i]*vz[i];
    const float th[4] = {th4.x, th4.y, th4.z, th4.w};

    // ---- build 4 step quats, serial pre-compose (keep all prefixes) ----
    Q4 q0, q1, q2, q3;
    BUILD_Q(0, q0); BUILD_Q(1, q1); BUILD_Q(2, q2); BUILD_Q(3, q3);
    const Q4 Q01   = qmul(q0, q1);
    const Q4 Q012  = qmul(Q01, q2);
    Q4 S           = qmul(Q012, q3);    // 4-step product

    // ---- 5-round W32 inclusive quat scan ----
    #pragma unroll
    for (int off = 1; off < 32; off <<= 1) {
        Q4 Qp; SHFL_Q_UP32(Qp, S, off);
        if (sl >= off) S = qmul(Qp, S);
    }
    Q4 E; SHFL_Q_UP32(E, S, 1);
    if (sl == 0) { E.w = 1.f; E.x = E.y = E.z = 0.f; }

    const Q4 Pq0 = qmul(E, q0);         // R(P_{4sl})
    const Q4 Pq1 = qmul(E, Q01);        // R(P_{4sl+1})
    const Q4 Pq2 = qmul(E, Q012);       // R(P_{4sl+2})
    // R(P_{4sl+3}) = S

    // ---- d_k = R(P_k)·(pos0[k+3]-pos0[k+1]) ----
    float d0x,d0y,d0z, d1x,d1y,d1z, d2x,d2y,d2z, d3x,d3y,d3z;
    qrotv(Pq0, A[9]-A[3],   A[10]-A[4],  A[11]-A[5],  d0x,d0y,d0z);
    qrotv(Pq1, A[12]-A[6],  A[13]-A[7],  A[14]-A[8],  d1x,d1y,d1z);
    qrotv(Pq2, A[15]-A[9],  A[16]-A[10], A[17]-A[11], d2x,d2y,d2z);
    qrotv(S,   A[18]-A[12], A[19]-A[13], A[20]-A[14], d3x,d3y,d3z);

    // ---- two float3 inclusive prefix sums (even-k chain, odd-k chain) ----
    float sex = d0x + d2x, sey = d0y + d2y, sez = d0z + d2z;
    float sox = d1x + d3x, soy = d1y + d3y, soz = d1z + d3z;
    #pragma unroll
    for (int off = 1; off < 32; off <<= 1) {
        const float ax = __shfl_up(sex, off, 32), ay = __shfl_up(sey, off, 32), az = __shfl_up(sez, off, 32);
        const float bx = __shfl_up(sox, off, 32), by = __shfl_up(soy, off, 32), bz = __shfl_up(soz, off, 32);
        if (sl >= off) { sex += ax; sey += ay; sez += az; sox += bx; soy += by; soz += bz; }
    }

    // final[4sl+3] = pos0[1] + Se - d2 ; final[4sl+5] = pos0[1] + Se
    // final[4sl+4] = pos0[2] + So - d3 ; final[4sl+6] = pos0[2] + So
    const float p1x = sa[3], p1y = sa[4], p1z = sa[5];
    const float p2x = sa[6], p2y = sa[7], p2z = sa[8];
    const float f3x = p1x + sex - d2x, f3y = p1y + sey - d2y, f3z = p1z + sez - d2z;
    const float f5x = p1x + sex,       f5y = p1y + sey,       f5z = p1z + sez;
    const float f4x = p2x + sox - d3x, f4y = p2y + soy - d3y, f4z = p2z + soz - d3z;
    const float f6x = p2x + sox,       f6y = p2y + soy,       f6z = p2z + soz;

    {
        float* op = &sout[12*sl + 9];
        op[0] = f3x; op[1]  = f3y; op[2]  = f3z;   // atom 4sl+3
        op[3] = f4x; op[4]  = f4y; op[5]  = f4z;   // atom 4sl+4
        op[6] = f5x; op[7]  = f5y; op[8]  = f5z;   // atom 4sl+5
        op[9] = f6x; op[10] = f6y; op[11] = f6z;   // atom 4sl+6
    }
    if (sl < 9) sout[sl] = sa[sl];     // atoms 0..2 never move

    // ---- F = P_127: rotation = S@sl31; translation from final[128] (=f4@sl31) ----
    float tFx = 0.f, tFy = 0.f, tFz = 0.f;
    if (sl == 31) {
        float rx, ry, rz;
        qrotv(S, sa[384], sa[385], sa[386], rx, ry, rz);   // R_F·pos0[128]
        tFx = f4x - rx; tFy = f4y - ry; tFz = f4z - rz;
        // atom 131 = F(pos0[131])
        qrotv(S, sa[393], sa[394], sa[395], rx, ry, rz);
        sout[393] = rx + tFx; sout[394] = ry + tFy; sout[395] = rz + tFz;
    }
    Q4 Fq;
    Fq.w = __shfl(S.w, 31, 32); Fq.x = __shfl(S.x, 31, 32);
    Fq.y = __shfl(S.y, 31, 32); Fq.z = __shfl(S.z, 31, 32);
    const float Ftx = __shfl(tFx, 31, 32), Fty = __shfl(tFy, 31, 32), Ftz = __shfl(tFz, 31, 32);
    const float f00 = 1.f - 2.f*(Fq.y*Fq.y + Fq.z*Fq.z);
    const float f01 = 2.f*(Fq.x*Fq.y - Fq.w*Fq.z);
    const float f02 = 2.f*(Fq.x*Fq.z + Fq.w*Fq.y);
    const float f10 = 2.f*(Fq.x*Fq.y + Fq.w*Fq.z);
    const float f11 = 1.f - 2.f*(Fq.x*Fq.x + Fq.z*Fq.z);
    const float f12 = 2.f*(Fq.y*Fq.z - Fq.w*Fq.x);
    const float f20 = 2.f*(Fq.x*Fq.z - Fq.w*Fq.y);
    const float f21 = 2.f*(Fq.y*Fq.z + Fq.w*Fq.x);
    const float f22 = 1.f - 2.f*(Fq.x*Fq.x + Fq.y*Fq.y);

    // ---- store head (99 f4) ----
    const float4* so4 = (const float4*)sout;
    ob4[sl] = so4[sl]; ob4[sl + 32] = so4[sl + 32]; ob4[sl + 64] = so4[sl + 64];
    if (ex) ob4[96 + sl] = so4[96 + sl];

    // ---- tail: 95 f4-triples per molecule, 3 per lane, data in registers ----
    #define TAIL_EMIT(b, va, vb, vc)                                          \
    do {                                                                      \
        const float x0=va.x, y0=va.y, z0=va.z;                                \
        const float x1=va.w, y1=vb.x, z1=vb.y;                                \
        const float x2=vb.z, y2=vb.w, z2=vc.x;                                \
        const float x3=vc.y, y3=vc.z, z3=vc.w;                                \
        float4 o0, o1, o2;                                                    \
        o0.x = f00*x0+f01*y0+f02*z0+Ftx; o0.y = f10*x0+f11*y0+f12*z0+Fty;     \
        o0.z = f20*x0+f21*y0+f22*z0+Ftz; o0.w = f00*x1+f01*y1+f02*z1+Ftx;     \
        o1.x = f10*x1+f11*y1+f12*z1+Fty; o1.y = f20*x1+f21*y1+f22*z1+Ftz;     \
        o1.z = f00*x2+f01*y2+f02*z2+Ftx; o1.w = f10*x2+f11*y2+f12*z2+Fty;     \
        o2.x = f20*x2+f21*y2+f22*z2+Ftz; o2.y = f00*x3+f01*y3+f02*z3+Ftx;     \
        o2.z = f10*x3+f11*y3+f12*z3+Fty; o2.w = f20*x3+f21*y3+f22*z3+Ftz;     \
        ob4[(b)] = o0; ob4[(b)+1] = o1; ob4[(b)+2] = o2;                      \
    } while (0)

    TAIL_EMIT(99 + 3*sl,        T0a, T0b, T0c);
    TAIL_EMIT(99 + 3*(sl + 32), T1a, T1b, T1c);
    if (has3) TAIL_EMIT(99 + 3*(sl + 64), T2a, T2b, T2c);
    #undef TAIL_EMIT
}

extern "C" void kernel_launch(void* const* d_in, const int* in_sizes, int n_in,
                              void* d_out, int out_size, void* d_ws, size_t ws_size,
                              hipStream_t stream) {
    const float* theta = (const float*)d_in[0];  // input (N,K) fp32
    const float* pos0  = (const float*)d_in[1];  // pos0 (N,M,3) fp32
    float* out = (float*)d_out;                  // (N,M,3) fp32
    dihedral_qscan_kernel<<<NMOL / (WPB * MPW), TPB, 0, stream>>>(theta, pos0, out);
}

// Round 15
// 16.826 us; speedup vs baseline: 1.2433x; 1.0223x over previous
//
#include <hip/hip_runtime.h>

// Dihedral2Coord — R14 (quat-only scan + parallel translation recurrence)
// with DPP cross-lane scan: row_shr/row_bcast15 (1-cyc VALU) replaces
// ds_bpermute (~30-40 cyc LDS pipe) in the 5-round W32 scans, and the
// exclusive prefix comes from E = S ⊗ conj(D) (no shuffle round at all).
//
// final[m] = P_{m-3}(pos0[m]); P_k = B_0⊗...⊗B_k (LOCAL-frame step
// rotations; dihedrals are rigid-invariant so phi_k comes from pos0 alone).
// final[k+3] = R(P_k)·(pos0[k+3]-pos0[k+1]) + final[k+1]  (2-stride chains).

#define NK 128
#define NM 512
#define NMOL 4096
#define TPB 256
#define WPB 4        // waves per block
#define MPW 2        // molecules per wave (two 32-lane segments)
// grid = NMOL/(WPB*MPW) = 512

struct Q4 { float w, x, y, z; };

__device__ __forceinline__ Q4 qmul(const Q4& a, const Q4& b) {
    Q4 r;
    r.w = a.w*b.w - a.x*b.x - a.y*b.y - a.z*b.z;
    r.x = a.w*b.x + a.x*b.w + a.y*b.z - a.z*b.y;
    r.y = a.w*b.y - a.x*b.z + a.y*b.w + a.z*b.x;
    r.z = a.w*b.z + a.x*b.y - a.y*b.x + a.z*b.w;
    return r;
}

__device__ __forceinline__ void qrotv(const Q4& q, float vx, float vy, float vz,
                                      float& ox, float& oy, float& oz) {
    const float ux = q.y*vz - q.z*vy + q.w*vx;
    const float uy = q.z*vx - q.x*vz + q.w*vy;
    const float uz = q.x*vy - q.y*vx + q.w*vz;
    ox = vx + 2.f*(q.y*uz - q.z*uy);
    oy = vy + 2.f*(q.z*ux - q.x*uz);
    oz = vz + 2.f*(q.x*uy - q.y*ux);
}

// ---- DPP cross-lane (gfx9/CDNA encodings) ----
// ROW_SHR:N = 0x110+N ; ROW_BCAST15 = 0x142. bound_ctrl=true -> invalid src = 0.
template <int CTRL, int RMASK>
__device__ __forceinline__ float dpp_mov(float x) {
    return __int_as_float(__builtin_amdgcn_update_dpp(
        0, __float_as_int(x), CTRL, RMASK, 0xF, true));
}

// Step-quat for step 4sl+j (validated sphi/cphi formula, R10-R14; quat only)
#define BUILD_Q(j, OUT) do {                                                  \
    const float cxx = ny[(j)+1]*nz[(j)] - nz[(j)+1]*ny[(j)];                  \
    const float cxy = nz[(j)+1]*nx[(j)] - nx[(j)+1]*nz[(j)];                  \
    const float cxz = nx[(j)+1]*ny[(j)] - ny[(j)+1]*nx[(j)];                  \
    const float g   = cxx*vx[(j)+1] + cxy*vy[(j)+1] + cxz*vz[(j)+1];          \
    const float dnn = nx[(j)]*nx[(j)+1] + ny[(j)]*ny[(j)+1] + nz[(j)]*nz[(j)+1]; \
    const float r12 = rsqrtf(fmaxf(Ln[(j)]*Ln[(j)+1], 1e-30f));               \
    const float ira = rsqrtf(fmaxf(Lv[(j)+1], 1e-24f));                       \
    const float cphi = dnn*r12, sphi = g*r12*ira;                             \
    const float sth = __sinf(th[(j)]), cth = __cosf(th[(j)]);                 \
    const float c = cth*cphi - sth*sphi, s = sth*cphi + cth*sphi;             \
    const float hc = sqrtf(fmaxf(0.f, 0.5f*(1.f + c)));                       \
    const float hs = copysignf(sqrtf(fmaxf(0.f, 0.5f*(1.f - c))), s);         \
    const float hsa = hs*ira;                                                 \
    OUT.w = hc; OUT.x = vx[(j)+1]*hsa; OUT.y = vy[(j)+1]*hsa; OUT.z = vz[(j)+1]*hsa; \
} while (0)

__global__ __launch_bounds__(TPB, 2) void dihedral_dpp_kernel(
    const float* __restrict__ theta,  // (NMOL, NK)
    const float* __restrict__ pos0,   // (NMOL, NM, 3)
    float* __restrict__ out)          // (NMOL, NM, 3)
{
    const int tid  = threadIdx.x;
    const int lane = tid & 63;
    const int wid  = tid >> 6;
    const int seg  = lane >> 5;      // which molecule of this wave
    const int sl   = lane & 31;      // segment lane
    const int mol  = blockIdx.x * (WPB * MPW) + wid * MPW + seg;

    const float4* __restrict__ pb4 = (const float4*)(pos0 + (size_t)mol * (NM*3));
    float4*       __restrict__ ob4 = (float4*)(out  + (size_t)mol * (NM*3));

    __shared__ float sAm[WPB][MPW][400];   // pos0 atoms 0..131
    __shared__ float sOm[WPB][MPW][400];   // final atoms 0..131
    float* __restrict__ sa   = sAm[wid][seg];
    float* __restrict__ sout = sOm[wid][seg];

    // ---- issue ALL global loads up front ----
    const bool ex = (sl < 3);
    float4 h0 = pb4[sl], h1 = pb4[sl + 32], h2 = pb4[sl + 64];
    float4 h3; if (ex) h3 = pb4[96 + sl];
    const float4 th4 = ((const float4*)(theta + (size_t)mol * NK))[sl];
    float4 T0a, T0b, T0c, T1a, T1b, T1c, T2a, T2b, T2c;
    { const int b = 99 + 3*sl;        T0a = pb4[b]; T0b = pb4[b+1]; T0c = pb4[b+2]; }
    { const int b = 99 + 3*(sl + 32); T1a = pb4[b]; T1b = pb4[b+1]; T1c = pb4[b+2]; }
    const bool has3 = (sl < 31);
    if (has3) { const int b = 99 + 3*(sl + 64); T2a = pb4[b]; T2b = pb4[b+1]; T2c = pb4[b+2]; }

    // stage head (same-wave DS ordering, no barrier)
    float4* sa4 = (float4*)sa;
    sa4[sl] = h0; sa4[sl + 32] = h1; sa4[sl + 64] = h2;
    if (ex) sa4[96 + sl] = h3;

    // lane: atoms 4sl..4sl+6 (21 floats)
    float A[21];
    {
        const float2* ap2 = (const float2*)&sa[sl * 12];
        #pragma unroll
        for (int i = 0; i < 10; ++i) { const float2 v = ap2[i]; A[2*i] = v.x; A[2*i+1] = v.y; }
        A[20] = sa[sl * 12 + 20];
    }

    // shared bonds / normals for the 4 steps
    float vx[6], vy[6], vz[6];
    #pragma unroll
    for (int i = 0; i < 6; ++i) {
        vx[i] = A[3*i+3] - A[3*i];
        vy[i] = A[3*i+4] - A[3*i+1];
        vz[i] = A[3*i+5] - A[3*i+2];
    }
    float nx[5], ny[5], nz[5], Ln[5];
    #pragma unroll
    for (int i = 0; i < 5; ++i) {
        nx[i] = vy[i]*vz[i+1] - vz[i]*vy[i+1];
        ny[i] = vz[i]*vx[i+1] - vx[i]*vz[i+1];
        nz[i] = vx[i]*vy[i+1] - vy[i]*vx[i+1];
        Ln[i] = nx[i]*nx[i] + ny[i]*ny[i] + nz[i]*nz[i];
    }
    float Lv[5];
    #pragma unroll
    for (int i = 1; i < 5; ++i) Lv[i] = vx[i]*vx[i] + vy[i]*vy[i] + vz[i]*vz[i];
    const float th[4] = {th4.x, th4.y, th4.z, th4.w};

    // ---- build 4 step quats, serial pre-compose (keep all prefixes) ----
    Q4 q0, q1, q2, q3;
    BUILD_Q(0, q0); BUILD_Q(1, q1); BUILD_Q(2, q2); BUILD_Q(3, q3);
    const Q4 Q01   = qmul(q0, q1);
    const Q4 Q012  = qmul(Q01, q2);
    const Q4 D     = qmul(Q012, q3);    // lane's 4-step product
    Q4 S = D;

    // ---- 5-round W32 inclusive quat scan via DPP ----
    const int rowi = sl & 15;
    #define QSCAN_ROUND(CTRL, COND)                                          \
    do {                                                                     \
        Q4 Qp;                                                               \
        Qp.w = dpp_mov<CTRL, 0xF>(S.w); Qp.x = dpp_mov<CTRL, 0xF>(S.x);      \
        Qp.y = dpp_mov<CTRL, 0xF>(S.y); Qp.z = dpp_mov<CTRL, 0xF>(S.z);      \
        if (COND) S = qmul(Qp, S);                                           \
    } while (0)
    QSCAN_ROUND(0x111, rowi >= 1);
    QSCAN_ROUND(0x112, rowi >= 2);
    QSCAN_ROUND(0x114, rowi >= 4);
    QSCAN_ROUND(0x118, rowi >= 8);
    QSCAN_ROUND(0x142, (lane & 16) != 0);   // row_bcast15: prepend lower row total
    #undef QSCAN_ROUND

    // exclusive prefix WITHOUT a shuffle: E = S ⊗ conj(D) (unit quats; lane0 -> id)
    Q4 Dc; Dc.w = D.w; Dc.x = -D.x; Dc.y = -D.y; Dc.z = -D.z;
    const Q4 E   = qmul(S, Dc);
    const Q4 Pq0 = qmul(E, q0);         // R(P_{4sl})
    const Q4 Pq1 = qmul(E, Q01);        // R(P_{4sl+1})
    const Q4 Pq2 = qmul(E, Q012);       // R(P_{4sl+2})
    // R(P_{4sl+3}) = S

    // ---- d_k = R(P_k)·(pos0[k+3]-pos0[k+1]) ----
    float d0x,d0y,d0z, d1x,d1y,d1z, d2x,d2y,d2z, d3x,d3y,d3z;
    qrotv(Pq0, A[9]-A[3],   A[10]-A[4],  A[11]-A[5],  d0x,d0y,d0z);
    qrotv(Pq1, A[12]-A[6],  A[13]-A[7],  A[14]-A[8],  d1x,d1y,d1z);
    qrotv(Pq2, A[15]-A[9],  A[16]-A[10], A[17]-A[11], d2x,d2y,d2z);
    qrotv(S,   A[18]-A[12], A[19]-A[13], A[20]-A[14], d3x,d3y,d3z);

    // ---- two float3 inclusive prefix sums via DPP (unconditional adds) ----
    float sex = d0x + d2x, sey = d0y + d2y, sez = d0z + d2z;
    float sox = d1x + d3x, soy = d1y + d3y, soz = d1z + d3z;
    #define SUM_ROUND(CTRL, RM)                                              \
    do {                                                                     \
        sex += dpp_mov<CTRL, RM>(sex); sey += dpp_mov<CTRL, RM>(sey);        \
        sez += dpp_mov<CTRL, RM>(sez);                                       \
        sox += dpp_mov<CTRL, RM>(sox); soy += dpp_mov<CTRL, RM>(soy);        \
        soz += dpp_mov<CTRL, RM>(soz);                                       \
    } while (0)
    SUM_ROUND(0x111, 0xF);   // invalid-in-row lanes add 0 (bound_ctrl)
    SUM_ROUND(0x112, 0xF);
    SUM_ROUND(0x114, 0xF);
    SUM_ROUND(0x118, 0xF);
    SUM_ROUND(0x142, 0xA);   // rows 1,3 add lower-row total; rows 0,2 add 0
    #undef SUM_ROUND

    // final[4sl+3] = pos0[1] + Se - d2 ; final[4sl+5] = pos0[1] + Se
    // final[4sl+4] = pos0[2] + So - d3 ; final[4sl+6] = pos0[2] + So
    const float p1x = sa[3], p1y = sa[4], p1z = sa[5];
    const float p2x = sa[6], p2y = sa[7], p2z = sa[8];
    const float f3x = p1x + sex - d2x, f3y = p1y + sey - d2y, f3z = p1z + sez - d2z;
    const float f5x = p1x + sex,       f5y = p1y + sey,       f5z = p1z + sez;
    const float f4x = p2x + sox - d3x, f4y = p2y + soy - d3y, f4z = p2z + soz - d3z;
    const float f6x = p2x + sox,       f6y = p2y + soy,       f6z = p2z + soz;

    {
        float* op = &sout[12*sl + 9];
        op[0] = f3x; op[1]  = f3y; op[2]  = f3z;   // atom 4sl+3
        op[3] = f4x; op[4]  = f4y; op[5]  = f4z;   // atom 4sl+4
        op[6] = f5x; op[7]  = f5y; op[8]  = f5z;   // atom 4sl+5
        op[9] = f6x; op[10] = f6y; op[11] = f6z;   // atom 4sl+6
    }
    if (sl < 9) sout[sl] = sa[sl];     // atoms 0..2 never move

    // ---- F = P_127: rotation = S@sl31; translation from final[128] (=f4@sl31) ----
    float tFx = 0.f, tFy = 0.f, tFz = 0.f;
    if (sl == 31) {
        float rx, ry, rz;
        qrotv(S, sa[384], sa[385], sa[386], rx, ry, rz);   // R_F·pos0[128]
        tFx = f4x - rx; tFy = f4y - ry; tFz = f4z - rz;
        // atom 131 = F(pos0[131])
        qrotv(S, sa[393], sa[394], sa[395], rx, ry, rz);
        sout[393] = rx + tFx; sout[394] = ry + tFy; sout[395] = rz + tFz;
    }
    Q4 Fq;
    Fq.w = __shfl(S.w, 31, 32); Fq.x = __shfl(S.x, 31, 32);
    Fq.y = __shfl(S.y, 31, 32); Fq.z = __shfl(S.z, 31, 32);
    const float Ftx = __shfl(tFx, 31, 32), Fty = __shfl(tFy, 31, 32), Ftz = __shfl(tFz, 31, 32);
    const float f00 = 1.f - 2.f*(Fq.y*Fq.y + Fq.z*Fq.z);
    const float f01 = 2.f*(Fq.x*Fq.y - Fq.w*Fq.z);
    const float f02 = 2.f*(Fq.x*Fq.z + Fq.w*Fq.y);
    const float f10 = 2.f*(Fq.x*Fq.y + Fq.w*Fq.z);
    const float f11 = 1.f - 2.f*(Fq.x*Fq.x + Fq.z*Fq.z);
    const float f12 = 2.f*(Fq.y*Fq.z - Fq.w*Fq.x);
    const float f20 = 2.f*(Fq.x*Fq.z - Fq.w*Fq.y);
    const float f21 = 2.f*(Fq.y*Fq.z + Fq.w*Fq.x);
    const float f22 = 1.f - 2.f*(Fq.x*Fq.x + Fq.y*Fq.y);

    // ---- store head (99 f4) ----
    const float4* so4 = (const float4*)sout;
    ob4[sl] = so4[sl]; ob4[sl + 32] = so4[sl + 32]; ob4[sl + 64] = so4[sl + 64];
    if (ex) ob4[96 + sl] = so4[96 + sl];

    // ---- tail: 95 f4-triples per molecule, 3 per lane, data in registers ----
    #define TAIL_EMIT(b, va, vb, vc)                                          \
    do {                                                                      \
        const float x0=va.x, y0=va.y, z0=va.z;                                \
        const float x1=va.w, y1=vb.x, z1=vb.y;                                \
        const float x2=vb.z, y2=vb.w, z2=vc.x;                                \
        const float x3=vc.y, y3=vc.z, z3=vc.w;                                \
        float4 o0, o1, o2;                                                    \
        o0.x = f00*x0+f01*y0+f02*z0+Ftx; o0.y = f10*x0+f11*y0+f12*z0+Fty;     \
        o0.z = f20*x0+f21*y0+f22*z0+Ftz; o0.w = f00*x1+f01*y1+f02*z1+Ftx;     \
        o1.x = f10*x1+f11*y1+f12*z1+Fty; o1.y = f20*x1+f21*y1+f22*z1+Ftz;     \
        o1.z = f00*x2+f01*y2+f02*z2+Ftx; o1.w = f10*x2+f11*y2+f12*z2+Fty;     \
        o2.x = f20*x2+f21*y2+f22*z2+Ftz; o2.y = f00*x3+f01*y3+f02*z3+Ftx;     \
        o2.z = f10*x3+f11*y3+f12*z3+Fty; o2.w = f20*x3+f21*y3+f22*z3+Ftz;     \
        ob4[(b)] = o0; ob4[(b)+1] = o1; ob4[(b)+2] = o2;                      \
    } while (0)

    TAIL_EMIT(99 + 3*sl,        T0a, T0b, T0c);
    TAIL_EMIT(99 + 3*(sl + 32), T1a, T1b, T1c);
    if (has3) TAIL_EMIT(99 + 3*(sl + 64), T2a, T2b, T2c);
    #undef TAIL_EMIT
}

extern "C" void kernel_launch(void* const* d_in, const int* in_sizes, int n_in,
                              void* d_out, int out_size, void* d_ws, size_t ws_size,
                              hipStream_t stream) {
    const float* theta = (const float*)d_in[0];  // input (N,K) fp32
    const float* pos0  = (const float*)d_in[1];  // pos0 (N,M,3) fp32
    float* out = (float*)d_out;                  // (N,M,3) fp32
    dihedral_dpp_kernel<<<NMOL / (WPB * MPW), TPB, 0, stream>>>(theta, pos0, out);
}

// Round 16
// 16.469 us; speedup vs baseline: 1.2703x; 1.0217x over previous
//
#include <hip/hip_runtime.h>

// Dihedral2Coord — 1 molecule per wave (16 waves/CU for memory TLP) with all
// accumulated compute wins: quat-only W64 DPP scan (row_shr×4 + bcast15 +
// bcast31), exclusive prefix E = S⊗conj(D) (no extra round), and 2-stride
// translation chains: final[2l+3] = pos0[1]+Σ_{j≤l} d_even(j),
// final[2l+4] = pos0[2]+Σ_{j≤l} d_odd(j), d = R(P_k)·(pos0[k+3]-pos0[k+1]).
//
// P_k = B_0⊗...⊗B_k (LOCAL-frame step rotations; dihedrals rigid-invariant).

#define NK 128
#define NM 512
#define NMOL 4096
#define TPB 256
#define WPB 4        // waves per block, 1 molecule per wave
// grid = NMOL/WPB = 1024 -> 4 blocks/CU -> 16 waves/CU

struct Q4 { float w, x, y, z; };

__device__ __forceinline__ Q4 qmul(const Q4& a, const Q4& b) {
    Q4 r;
    r.w = a.w*b.w - a.x*b.x - a.y*b.y - a.z*b.z;
    r.x = a.w*b.x + a.x*b.w + a.y*b.z - a.z*b.y;
    r.y = a.w*b.y - a.x*b.z + a.y*b.w + a.z*b.x;
    r.z = a.w*b.z + a.x*b.y - a.y*b.x + a.z*b.w;
    return r;
}

__device__ __forceinline__ void qrotv(const Q4& q, float vx, float vy, float vz,
                                      float& ox, float& oy, float& oz) {
    const float ux = q.y*vz - q.z*vy + q.w*vx;
    const float uy = q.z*vx - q.x*vz + q.w*vy;
    const float uz = q.x*vy - q.y*vx + q.w*vz;
    ox = vx + 2.f*(q.y*uz - q.z*uy);
    oy = vy + 2.f*(q.z*ux - q.x*uz);
    oz = vz + 2.f*(q.x*uy - q.y*ux);
}

// DPP: ROW_SHR:N = 0x110+N ; ROW_BCAST15 = 0x142 ; ROW_BCAST31 = 0x143.
// old=0 + row_mask -> unselected rows yield 0 (used by the unconditional sums).
template <int CTRL, int RMASK>
__device__ __forceinline__ float dpp_mov(float x) {
    return __int_as_float(__builtin_amdgcn_update_dpp(
        0, __float_as_int(x), CTRL, RMASK, 0xF, true));
}

// Step-quat for step 2l+j (validated sphi/cphi formula, R10-R15; quat only)
#define BUILD_Q(j, OUT) do {                                                  \
    const float cxx = ny[(j)+1]*nz[(j)] - nz[(j)+1]*ny[(j)];                  \
    const float cxy = nz[(j)+1]*nx[(j)] - nx[(j)+1]*nz[(j)];                  \
    const float cxz = nx[(j)+1]*ny[(j)] - ny[(j)+1]*nx[(j)];                  \
    const float g   = cxx*vx[(j)+1] + cxy*vy[(j)+1] + cxz*vz[(j)+1];          \
    const float dnn = nx[(j)]*nx[(j)+1] + ny[(j)]*ny[(j)+1] + nz[(j)]*nz[(j)+1]; \
    const float r12 = rsqrtf(fmaxf(Ln[(j)]*Ln[(j)+1], 1e-30f));               \
    const float ira = rsqrtf(fmaxf(Lv[(j)+1], 1e-24f));                       \
    const float cphi = dnn*r12, sphi = g*r12*ira;                             \
    const float sth = __sinf(th[(j)]), cth = __cosf(th[(j)]);                 \
    const float c = cth*cphi - sth*sphi, s = sth*cphi + cth*sphi;             \
    const float hc = sqrtf(fmaxf(0.f, 0.5f*(1.f + c)));                       \
    const float hs = copysignf(sqrtf(fmaxf(0.f, 0.5f*(1.f - c))), s);         \
    const float hsa = hs*ira;                                                 \
    OUT.w = hc; OUT.x = vx[(j)+1]*hsa; OUT.y = vy[(j)+1]*hsa; OUT.z = vz[(j)+1]*hsa; \
} while (0)

__global__ __launch_bounds__(TPB, 4) void dihedral_w64_kernel(
    const float* __restrict__ theta,  // (NMOL, NK)
    const float* __restrict__ pos0,   // (NMOL, NM, 3)
    float* __restrict__ out)          // (NMOL, NM, 3)
{
    const int tid  = threadIdx.x;
    const int lane = tid & 63;
    const int wid  = tid >> 6;
    const int mol  = blockIdx.x * WPB + wid;

    const float4* __restrict__ pb4 = (const float4*)(pos0 + (size_t)mol * (NM*3));
    float4*       __restrict__ ob4 = (float4*)(out  + (size_t)mol * (NM*3));

    __shared__ float sAm[WPB][400];   // pos0 atoms 0..131
    __shared__ float sOm[WPB][400];   // final atoms 0..131
    float* __restrict__ sa   = sAm[wid];
    float* __restrict__ sout = sOm[wid];

    // ---- issue ALL global loads up front ----
    const bool ex   = (lane < 35);
    const bool has2 = (lane < 31);   // tail tasks 64..94
    float4 h0 = pb4[lane];
    float4 h1; if (ex) h1 = pb4[64 + lane];
    const float2 th2 = ((const float2*)(theta + (size_t)mol * NK))[lane];
    float4 T0a, T0b, T0c, T1a, T1b, T1c;
    { const int b = 99 + 3*lane; T0a = pb4[b]; T0b = pb4[b+1]; T0c = pb4[b+2]; }
    if (has2) { const int b = 99 + 3*(64 + lane); T1a = pb4[b]; T1b = pb4[b+1]; T1c = pb4[b+2]; }

    // stage head (same-wave DS ordering, no barrier)
    float4* sa4 = (float4*)sa;
    sa4[lane] = h0;
    if (ex) sa4[64 + lane] = h1;

    // lane l: atoms 2l..2l+4 (15 floats)
    float A[16];
    {
        const float2* ap2 = (const float2*)&sa[lane * 6];
        #pragma unroll
        for (int i = 0; i < 7; ++i) { const float2 v = ap2[i]; A[2*i] = v.x; A[2*i+1] = v.y; }
        A[14] = sa[lane * 6 + 14];
    }

    // bonds / normals for the 2 steps
    float vx[4], vy[4], vz[4];
    #pragma unroll
    for (int i = 0; i < 4; ++i) {
        vx[i] = A[3*i+3] - A[3*i];
        vy[i] = A[3*i+4] - A[3*i+1];
        vz[i] = A[3*i+5] - A[3*i+2];
    }
    float nx[3], ny[3], nz[3], Ln[3];
    #pragma unroll
    for (int i = 0; i < 3; ++i) {
        nx[i] = vy[i]*vz[i+1] - vz[i]*vy[i+1];
        ny[i] = vz[i]*vx[i+1] - vx[i]*vz[i+1];
        nz[i] = vx[i]*vy[i+1] - vy[i]*vx[i+1];
        Ln[i] = nx[i]*nx[i] + ny[i]*ny[i] + nz[i]*nz[i];
    }
    float Lv[3];
    #pragma unroll
    for (int i = 1; i < 3; ++i) Lv[i] = vx[i]*vx[i] + vy[i]*vy[i] + vz[i]*vz[i];
    const float th[2] = {th2.x, th2.y};

    // ---- build 2 step quats; D = q0⊗q1 ----
    Q4 q0, q1;
    BUILD_Q(0, q0); BUILD_Q(1, q1);
    const Q4 D = qmul(q0, q1);
    Q4 S = D;

    // ---- 6-round W64 inclusive quat scan via DPP ----
    const int rowi = lane & 15;
    #define QSCAN_ROUND(CTRL, COND)                                          \
    do {                                                                     \
        Q4 Qp;                                                               \
        Qp.w = dpp_mov<CTRL, 0xF>(S.w); Qp.x = dpp_mov<CTRL, 0xF>(S.x);      \
        Qp.y = dpp_mov<CTRL, 0xF>(S.y); Qp.z = dpp_mov<CTRL, 0xF>(S.z);      \
        if (COND) S = qmul(Qp, S);                                           \
    } while (0)
    QSCAN_ROUND(0x111, rowi >= 1);
    QSCAN_ROUND(0x112, rowi >= 2);
    QSCAN_ROUND(0x114, rowi >= 4);
    QSCAN_ROUND(0x118, rowi >= 8);
    QSCAN_ROUND(0x142, (lane & 16) != 0);   // rows 1,3: prepend lower-row total
    QSCAN_ROUND(0x143, (lane & 32) != 0);   // rows 2,3: prepend rows0-1 total
    #undef QSCAN_ROUND

    // exclusive prefix: E = S ⊗ conj(D)  (unit quats; lane0 -> identity)
    Q4 Dc; Dc.w = D.w; Dc.x = -D.x; Dc.y = -D.y; Dc.z = -D.z;
    const Q4 E  = qmul(S, Dc);
    const Q4 Pe = qmul(E, q0);          // R(P_{2l});  R(P_{2l+1}) = S

    // ---- d = R(P_k)·(pos0[k+3]-pos0[k+1]) ----
    float dex, dey, dez, dox, doy, doz;
    qrotv(Pe, A[9]-A[3],  A[10]-A[4], A[11]-A[5], dex, dey, dez);
    qrotv(S,  A[12]-A[6], A[13]-A[7], A[14]-A[8], dox, doy, doz);

    // ---- two float3 inclusive prefix sums via DPP (unconditional adds) ----
    float sex = dex, sey = dey, sez = dez;
    float sox = dox, soy = doy, soz = doz;
    #define SUM_ROUND(CTRL, RM)                                              \
    do {                                                                     \
        sex += dpp_mov<CTRL, RM>(sex); sey += dpp_mov<CTRL, RM>(sey);        \
        sez += dpp_mov<CTRL, RM>(sez);                                       \
        sox += dpp_mov<CTRL, RM>(sox); soy += dpp_mov<CTRL, RM>(soy);        \
        soz += dpp_mov<CTRL, RM>(soz);                                       \
    } while (0)
    SUM_ROUND(0x111, 0xF);
    SUM_ROUND(0x112, 0xF);
    SUM_ROUND(0x114, 0xF);
    SUM_ROUND(0x118, 0xF);
    SUM_ROUND(0x142, 0xA);   // rows 1,3 add lower-row total; rows 0,2 add 0
    SUM_ROUND(0x143, 0xC);   // rows 2,3 add rows0-1 total; rows 0,1 add 0
    #undef SUM_ROUND

    // final[2l+3] = pos0[1] + Se ; final[2l+4] = pos0[2] + So
    const float p1x = sa[3], p1y = sa[4], p1z = sa[5];
    const float p2x = sa[6], p2y = sa[7], p2z = sa[8];
    const float fex = p1x + sex, fey = p1y + sey, fez = p1z + sez;
    const float fox = p2x + sox, foy = p2y + soy, foz = p2z + soz;

    {
        float* op = &sout[6*lane + 9];
        op[0] = fex; op[1] = fey; op[2] = fez;   // atom 2l+3
        op[3] = fox; op[4] = foy; op[5] = foz;   // atom 2l+4
    }
    if (lane < 9) sout[lane] = sa[lane];   // atoms 0..2 never move

    // ---- F = P_127 (S@63); translation from final[130] = fo@63 ----
    float tFx = 0.f, tFy = 0.f, tFz = 0.f;
    if (lane == 63) {
        float rx, ry, rz;
        qrotv(S, sa[390], sa[391], sa[392], rx, ry, rz);   // R_F·pos0[130]
        tFx = fox - rx; tFy = foy - ry; tFz = foz - rz;
        // atom 131 = F(pos0[131])
        qrotv(S, sa[393], sa[394], sa[395], rx, ry, rz);
        sout[393] = rx + tFx; sout[394] = ry + tFy; sout[395] = rz + tFz;
    }
    Q4 Fq;
    Fq.w = __shfl(S.w, 63, 64); Fq.x = __shfl(S.x, 63, 64);
    Fq.y = __shfl(S.y, 63, 64); Fq.z = __shfl(S.z, 63, 64);
    const float Ftx = __shfl(tFx, 63, 64), Fty = __shfl(tFy, 63, 64), Ftz = __shfl(tFz, 63, 64);
    const float f00 = 1.f - 2.f*(Fq.y*Fq.y + Fq.z*Fq.z);
    const float f01 = 2.f*(Fq.x*Fq.y - Fq.w*Fq.z);
    const float f02 = 2.f*(Fq.x*Fq.z + Fq.w*Fq.y);
    const float f10 = 2.f*(Fq.x*Fq.y + Fq.w*Fq.z);
    const float f11 = 1.f - 2.f*(Fq.x*Fq.x + Fq.z*Fq.z);
    const float f12 = 2.f*(Fq.y*Fq.z - Fq.w*Fq.x);
    const float f20 = 2.f*(Fq.x*Fq.z - Fq.w*Fq.y);
    const float f21 = 2.f*(Fq.y*Fq.z + Fq.w*Fq.x);
    const float f22 = 1.f - 2.f*(Fq.x*Fq.x + Fq.y*Fq.y);

    // ---- store head (99 f4) ----
    const float4* so4 = (const float4*)sout;
    ob4[lane] = so4[lane];
    if (ex) ob4[64 + lane] = so4[64 + lane];

    // ---- tail: 95 f4-triples, up to 2 per lane, data already in registers ----
    #define TAIL_EMIT(b, va, vb, vc)                                          \
    do {                                                                      \
        const float x0=va.x, y0=va.y, z0=va.z;                                \
        const float x1=va.w, y1=vb.x, z1=vb.y;                                \
        const float x2=vb.z, y2=vb.w, z2=vc.x;                                \
        const float x3=vc.y, y3=vc.z, z3=vc.w;                                \
        float4 o0, o1, o2;                                                    \
        o0.x = f00*x0+f01*y0+f02*z0+Ftx; o0.y = f10*x0+f11*y0+f12*z0+Fty;     \
        o0.z = f20*x0+f21*y0+f22*z0+Ftz; o0.w = f00*x1+f01*y1+f02*z1+Ftx;     \
        o1.x = f10*x1+f11*y1+f12*z1+Fty; o1.y = f20*x1+f21*y1+f22*z1+Ftz;     \
        o1.z = f00*x2+f01*y2+f02*z2+Ftx; o1.w = f10*x2+f11*y2+f12*z2+Fty;     \
        o2.x = f20*x2+f21*y2+f22*z2+Ftz; o2.y = f00*x3+f01*y3+f02*z3+Ftx;     \
        o2.z = f10*x3+f11*y3+f12*z3+Fty; o2.w = f20*x3+f21*y3+f22*z3+Ftz;     \
        ob4[(b)] = o0; ob4[(b)+1] = o1; ob4[(b)+2] = o2;                      \
    } while (0)

    TAIL_EMIT(99 + 3*lane, T0a, T0b, T0c);
    if (has2) TAIL_EMIT(99 + 3*(64 + lane), T1a, T1b, T1c);
    #undef TAIL_EMIT
}

extern "C" void kernel_launch(void* const* d_in, const int* in_sizes, int n_in,
                              void* d_out, int out_size, void* d_ws, size_t ws_size,
                              hipStream_t stream) {
    const float* theta = (const float*)d_in[0];  // input (N,K) fp32
    const float* pos0  = (const float*)d_in[1];  // pos0 (N,M,3) fp32
    float* out = (float*)d_out;                  // (N,M,3) fp32
    dihedral_w64_kernel<<<NMOL / WPB, TPB, 0, stream>>>(theta, pos0, out);
}